// Round 9
// baseline (359.282 us; speedup 1.0000x reference)
//
#include <hip/hip_runtime.h>
#include <hip/hip_bf16.h>
#include <stdint.h>

#define NB 32
#define NR 2048
#define NC 64
#define NO 64
#define NK 16

__device__ __forceinline__ uint32_t f2bf(float f) {
  uint32_t u = __builtin_bit_cast(uint32_t, f);
  return (u + 0x7fffu + ((u >> 16) & 1u)) >> 16;  // RNE
}
__device__ __forceinline__ uint32_t packbf2(float lo, float hi) {
  return f2bf(lo) | (f2bf(hi) << 16);
}

// x[b][r][c] -> xT[r][c][q] with PERMUTED b: position q holds b(q) = (q&3)*8 + (q>>2).
// So a float4 at q = bg*4.. holds b = {bg, 8+bg, 16+bg, 24+bg} -> the GEMM's
// store instr a (b = a*8+bg) is 1KB-contiguous across the wave.
__global__ __launch_bounds__(256) void transpose_x(const float* __restrict__ x,
                                                   float* __restrict__ xT) {
  __shared__ float tile[32][65];
  const int r = blockIdx.x, t = threadIdx.x;
  {
    const int b = t >> 3, c0 = (t & 7) << 3;
    const float* xp = x + ((size_t)b * NR + r) * NC + c0;
    float4 v0 = *(const float4*)xp;
    float4 v1 = *(const float4*)(xp + 4);
    tile[b][c0 + 0] = v0.x; tile[b][c0 + 1] = v0.y; tile[b][c0 + 2] = v0.z; tile[b][c0 + 3] = v0.w;
    tile[b][c0 + 4] = v1.x; tile[b][c0 + 5] = v1.y; tile[b][c0 + 6] = v1.z; tile[b][c0 + 7] = v1.w;
  }
  __syncthreads();
  {
    const int c = t >> 2, q0 = (t & 3) << 3;
    float v[8];
#pragma unroll
    for (int i = 0; i < 8; ++i) {
      const int q = q0 + i;
      v[i] = tile[(q & 3) * 8 + (q >> 2)][c];  // b(q)
    }
    float* op = xT + ((size_t)r * NC + c) * NB + q0;
    *(float4*)op = make_float4(v[0], v[1], v[2], v[3]);
    *(float4*)(op + 4) = make_float4(v[4], v[5], v[6], v[7]);
  }
}

// LDS-FREE register-streaming GEMM. R8 post-mortem: 3 ds_read_b128 per 32
// FMA/lane made the per-CU LDS unit 2.25x oversubscribed vs VALU (~123us of
// the 211us GEMM); LDS had zero cross-wave reuse (pure staging). Here each
// wave owns one (k,r) task, loads operands global->VGPR (each reg reused 32x
// by acc[4][8]), 2-c chunks in an explicit 3-deep named rotation (A/B/C,
// static indexing) so ~12-18 independent loads stay in flight per wave.
// No barriers. 16 consecutive tasks share one xT row -> L2-hot.
#define LOADS(S, t)                                                  \
  do {                                                               \
    const int c0_ = (t) * 2;                                         \
    _Pragma("unroll") for (int i = 0; i < 2; ++i) {                  \
      wa##S[i] = *(const float4*)(wp + (c0_ + i) * NO);              \
      wb##S[i] = *(const float4*)(wp + (c0_ + i) * NO + 4);          \
      x##S[i]  = *(const float4*)(xp + (c0_ + i) * NB);              \
    }                                                                \
  } while (0)

#define COMPS(S)                                                     \
  do {                                                               \
    _Pragma("unroll") for (int i = 0; i < 2; ++i) {                  \
      float xr[4] = {x##S[i].x, x##S[i].y, x##S[i].z, x##S[i].w};    \
      float wr[8] = {wa##S[i].x, wa##S[i].y, wa##S[i].z, wa##S[i].w, \
                     wb##S[i].x, wb##S[i].y, wb##S[i].z, wb##S[i].w};\
      _Pragma("unroll") for (int a = 0; a < 4; ++a)                  \
        _Pragma("unroll") for (int b = 0; b < 8; ++b)                \
          acc[a][b] = fmaf(xr[a], wr[b], acc[a][b]);                 \
    }                                                                \
  } while (0)

__global__ __launch_bounds__(256, 3) void priors_gemm(const float* __restrict__ xT,
                                                      const float* __restrict__ W,
                                                      __hip_bfloat16* __restrict__ priors) {
  const int w = threadIdx.x >> 6, lane = threadIdx.x & 63;
  const int bg = lane >> 3, og = lane & 7;
  const int task = blockIdx.x * 4 + w;   // 16 consecutive tasks: same r, k=0..15
  const int k = task & 15;
  const int r = task >> 4;

  const float* wp = W + ((size_t)k * NR + r) * (NC * NO) + og * 8;
  const float* xp = xT + (size_t)r * (NC * NB) + bg * 4;

  float acc[4][8] = {};
  float4 xA[2], waA[2], wbA[2];
  float4 xB[2], waB[2], wbB[2];
  float4 xC[2], waC[2], wbC[2];

  LOADS(A, 0);
  LOADS(B, 1);
  LOADS(C, 2);
#pragma unroll
  for (int t = 0; t < 32; t += 3) {
    COMPS(A);
    if (t + 3 < 32) LOADS(A, t + 3);
    if (t + 1 < 32) {
      COMPS(B);
      if (t + 4 < 32) LOADS(B, t + 4);
    }
    if (t + 2 < 32) {
      COMPS(C);
      if (t + 5 < 32) LOADS(C, t + 5);
    }
  }

  // acc[a][*] is b = a*8 + bg (permuted xT). Store instr a: og-lanes 128B x
  // bg-lanes 8 consecutive b's = 1KB contiguous; 4 instrs = dense 4KB r-slab.
#pragma unroll
  for (int a = 0; a < 4; ++a) {
    uint4 uv;
    uv.x = packbf2(acc[a][0], acc[a][1]);
    uv.y = packbf2(acc[a][2], acc[a][3]);
    uv.z = packbf2(acc[a][4], acc[a][5]);
    uv.w = packbf2(acc[a][6], acc[a][7]);
    __hip_bfloat16* pp = priors + ((size_t)(k * NR + r) * NB + a * 8 + bg) * NO + og * 8;
    *(uint4*)pp = uv;
  }
}

// Routing pass. Block per kb (k = kb>>5, b = kb&31). Lane: g = lane/8, sl = lane%8.
// priors layout [k][r][b][o] (natural b): read addr = ((r*NB + b)*NO + sl*8),
// 128B per r, 4KB stride -> served by L2/L3 (priors = 128MB, L3-resident).
// PASS==1: phase A computes o0 = squash(mean_r p) in-block (priors read #1);
//          phase B: l = a_r = p.o0, stores a_r, writes o1 (priors read #2, L3-hot).
// PASS==2: l = a_r + p.o1; writes final output.
template <int PASS>
__global__ __launch_bounds__(256) void routing(const __hip_bfloat16* __restrict__ priors,
                                               float* __restrict__ Abuf,
                                               const float* __restrict__ o_prev,
                                               float* __restrict__ o_out) {
  __shared__ float o_lds[64];
  __shared__ float red_num[4][8][8];
  __shared__ float red_den[4];
  const int kb = blockIdx.x;
  const int k = kb >> 5, b = kb & 31;
  const int tid = threadIdx.x, w = tid >> 6, lane = tid & 63;
  const int g = lane >> 3, sl = lane & 7;
  const int rsub = w * 8 + g;
  const __hip_bfloat16* pbase = priors + (size_t)k * NR * NB * NO + (size_t)b * NO;
  float* ab = Abuf + (size_t)kb * NR;

  if (PASS == 1) {
    // phase A: column-sum over r -> mean -> squash -> o0
    float sum[8];
#pragma unroll
    for (int j = 0; j < 8; ++j) sum[j] = 0.f;
    for (int it = 0; it < NR / 32; ++it) {
      const int r = it * 32 + rsub;
      uint4 pv = *(const uint4*)(pbase + (size_t)r * (NB * NO) + sl * 8);
      sum[0] += __builtin_bit_cast(float, pv.x << 16);
      sum[1] += __builtin_bit_cast(float, pv.x & 0xffff0000u);
      sum[2] += __builtin_bit_cast(float, pv.y << 16);
      sum[3] += __builtin_bit_cast(float, pv.y & 0xffff0000u);
      sum[4] += __builtin_bit_cast(float, pv.z << 16);
      sum[5] += __builtin_bit_cast(float, pv.z & 0xffff0000u);
      sum[6] += __builtin_bit_cast(float, pv.w << 16);
      sum[7] += __builtin_bit_cast(float, pv.w & 0xffff0000u);
    }
#pragma unroll
    for (int m = 8; m < 64; m <<= 1)
#pragma unroll
      for (int j = 0; j < 8; ++j) sum[j] += __shfl_xor(sum[j], m, 64);
    if (lane < 8) {
#pragma unroll
      for (int j = 0; j < 8; ++j) red_num[w][lane][j] = sum[j];
    }
    __syncthreads();
    if (tid < 64) {
      const int s_ = tid >> 3, j_ = tid & 7;
      float sv = (red_num[0][s_][j_] + red_num[1][s_][j_] +
                  red_num[2][s_][j_] + red_num[3][s_][j_]) * (1.f / (float)NR);
      float sq = sv * sv;
#pragma unroll
      for (int m = 1; m < 64; m <<= 1) sq += __shfl_xor(sq, m, 64);
      o_lds[tid] = (sq / (1.f + sq)) * rsqrtf(sq) * sv;  // squash
    }
    __syncthreads();
  } else {
    if (tid < 64) o_lds[tid] = o_prev[kb * 64 + tid];
    __syncthreads();
  }

  float os[8];
#pragma unroll
  for (int j = 0; j < 8; ++j) os[j] = o_lds[sl * 8 + j];

  float num[8];
#pragma unroll
  for (int j = 0; j < 8; ++j) num[j] = 0.f;
  float den = 0.f;

  for (int it = 0; it < NR / 32; ++it) {
    const int r = it * 32 + rsub;
    uint4 pv = *(const uint4*)(pbase + (size_t)r * (NB * NO) + sl * 8);
    float f[8];
    f[0] = __builtin_bit_cast(float, pv.x << 16);
    f[1] = __builtin_bit_cast(float, pv.x & 0xffff0000u);
    f[2] = __builtin_bit_cast(float, pv.y << 16);
    f[3] = __builtin_bit_cast(float, pv.y & 0xffff0000u);
    f[4] = __builtin_bit_cast(float, pv.z << 16);
    f[5] = __builtin_bit_cast(float, pv.z & 0xffff0000u);
    f[6] = __builtin_bit_cast(float, pv.w << 16);
    f[7] = __builtin_bit_cast(float, pv.w & 0xffff0000u);

    float d = 0.f;
#pragma unroll
    for (int j = 0; j < 8; ++j) d = fmaf(f[j], os[j], d);
#pragma unroll
    for (int m = 1; m < 8; m <<= 1) d += __shfl_xor(d, m, 64);  // dot over the 8-lane group

    float lg;
    if (PASS == 1) {
      lg = d;
      if (sl == 0) ab[r] = d;
    } else {
      lg = d + ab[r];
    }
    float e = __expf(lg);  // |lg| << 1, no max-subtraction needed
    den += e;
#pragma unroll
    for (int j = 0; j < 8; ++j) num[j] = fmaf(e, f[j], num[j]);
  }

#pragma unroll
  for (int m = 8; m < 64; m <<= 1) {
    den += __shfl_xor(den, m, 64);
#pragma unroll
    for (int j = 0; j < 8; ++j) num[j] += __shfl_xor(num[j], m, 64);
  }
  if (lane < 8) {
#pragma unroll
    for (int j = 0; j < 8; ++j) red_num[w][lane][j] = num[j];
    if (lane == 0) red_den[w] = den;
  }
  __syncthreads();

  if (tid < 64) {
    const int s_ = tid >> 3, j_ = tid & 7;
    float nm = red_num[0][s_][j_] + red_num[1][s_][j_] + red_num[2][s_][j_] + red_num[3][s_][j_];
    float dn = red_den[0] + red_den[1] + red_den[2] + red_den[3];
    float sv = nm / dn;
    float sq = sv * sv;
#pragma unroll
    for (int m = 1; m < 64; m <<= 1) sq += __shfl_xor(sq, m, 64);
    float ov = (sq / (1.f + sq)) * rsqrtf(sq) * sv;
    o_out[kb * 64 + tid] = ov;
  }
}

extern "C" void kernel_launch(void* const* d_in, const int* in_sizes, int n_in,
                              void* d_out, int out_size, void* d_ws, size_t ws_size,
                              hipStream_t stream) {
  const float* x = (const float*)d_in[0];          // [B][R][CIN]
  const float* W = (const float*)d_in[1];          // [K][R][CIN][COUT]
  float* out = (float*)d_out;                      // [K][B][COUT]
  char* ws = (char*)d_ws;

  size_t off = 0;
  float* xT = (float*)(ws + off);                  off += (size_t)NR * NC * NB * 4;        // 16 MB
  __hip_bfloat16* priors = (__hip_bfloat16*)(ws + off); off += (size_t)NK * NB * NR * NO * 2; // 128 MB
  float* o1 = (float*)(ws + off);                  off += (size_t)NK * NB * NO * 4;        // 128 KB
  float* Abuf = (float*)(ws + off);                off += (size_t)NK * NB * NR * 4;        // 4 MB

  transpose_x<<<NR, 256, 0, stream>>>(x, xT);
  priors_gemm<<<(NR * NK) / 4, 256, 0, stream>>>(xT, W, priors);
  routing<1><<<NK * NB, 256, 0, stream>>>(priors, Abuf, nullptr, o1);
  routing<2><<<NK * NB, 256, 0, stream>>>(priors, Abuf, o1, out);
}

// Round 10
// 240.670 us; speedup vs baseline: 1.4928x; 1.4928x over previous
//
#include <hip/hip_runtime.h>
#include <hip/hip_bf16.h>
#include <stdint.h>

#define NB 32
#define NR 2048
#define NC 64
#define NO 64
#define NK 16

using bf16x8 = __attribute__((ext_vector_type(8))) short;
using f32x4  = __attribute__((ext_vector_type(4))) float;

__device__ __forceinline__ uint32_t f2bf(float f) {
  uint32_t u = __builtin_bit_cast(uint32_t, f);
  return (u + 0x7fffu + ((u >> 16) & 1u)) >> 16;  // RNE
}
__device__ __forceinline__ uint32_t packbf2(float lo, float hi) {
  return f2bf(lo) | (f2bf(hi) << 16);
}

__device__ __forceinline__ void gload_lds16(const float* g, float* l) {
  __builtin_amdgcn_global_load_lds(
      (const __attribute__((address_space(1))) void*)g,
      (__attribute__((address_space(3))) void*)l, 16, 0, 0);
}

// x[b][r][c] -> xbf[r][ks][mt][lane][e] bf16 (A-fragment order).
// Slot (lane,e) of frag (ks,mt) holds x[b = mt*16 + (lane&15)]
//                                     [c = ks*32 + (lane>>4)*8 + e].
// Same slot->c map is used for the B operand in the GEMM, so the HW k-order
// cancels (consistent-slot argument) regardless of the true fragment layout.
__global__ __launch_bounds__(256) void make_xbf(const float* __restrict__ x,
                                                ushort* __restrict__ xbf) {
  __shared__ float tile[32][72];
  const int r = blockIdx.x, t = threadIdx.x;
  {
    const int b = t >> 3, c0 = (t & 7) << 3;
    const float* xp = x + ((size_t)b * NR + r) * NC + c0;
    *(float4*)&tile[b][c0] = *(const float4*)xp;
    *(float4*)&tile[b][c0 + 4] = *(const float4*)(xp + 4);
  }
  __syncthreads();
  {
    const int ks = t >> 7, mt = (t >> 6) & 1, l = t & 63;
    const int b = mt * 16 + (l & 15);
    const int cb = ks * 32 + (l >> 4) * 8;
    uint4 uv;
    uv.x = packbf2(tile[b][cb + 0], tile[b][cb + 1]);
    uv.y = packbf2(tile[b][cb + 2], tile[b][cb + 3]);
    uv.z = packbf2(tile[b][cb + 4], tile[b][cb + 5]);
    uv.w = packbf2(tile[b][cb + 6], tile[b][cb + 7]);
    *(uint4*)(xbf + (size_t)r * 2048 + t * 8) = uv;
  }
}

// MFMA GEMM with the R4-proven global_load_lds double-buffer conveyor.
// Block = (kq: 4 k's, rblk: 8 r's); wave w owns k = kq*4+w; chunk = one
// MFMA K-step (32 c): stage W fp32 [32c][64o] (8KB/wave) -> buf ks; compute:
// 2 A-frags (global bf16, L2-hot), 4 B-frags (8 ds_read_b32 + bf16 pack each),
// 8 x mfma_f32_16x16x32_bf16 into acc[2][4]. Epilogue per r: acc -> bf16 via
// wave-private LDS bounce (reuses own buf1 panel after reads) -> 1KB-contig
// global stores into natural priors[k][r][b][o].
__global__ __launch_bounds__(256, 2) void priors_gemm(const ushort* __restrict__ xbf,
                                                      const float* __restrict__ W,
                                                      ushort* __restrict__ priors) {
  __shared__ float ldsW[2][4][2048];  // [buf][wave][32c x 64o] fp32, 64KB
  const int w = threadIdx.x >> 6, lane = threadIdx.x & 63;
  const int g = lane >> 4, col = lane & 15;
  const int kq = blockIdx.x & 3, rblk = blockIdx.x >> 2;  // consecutive bids share rblk -> xbf L2-hot
  const int k = kq * 4 + w;

  f32x4 acc[2][4];

  auto stage = [&](int rr, int ks, int buf) {
    const float* src = W + ((size_t)(k * NR + rblk * 8 + rr)) * 4096 + ks * 2048 + lane * 4;
    float* dst = &ldsW[buf][w][0] + lane * 4;
#pragma unroll
    for (int i = 0; i < 8; ++i) gload_lds16(src + i * 256, dst + i * 256);
  };

  auto compute = [&](int rr, int ks, int buf) {
    const float* pw = &ldsW[buf][w][0];
    const size_t r = rblk * 8 + rr;
    bf16x8 af0 = *(const bf16x8*)(xbf + ((r * 2 + ks) * 2 + 0) * 512 + lane * 8);
    bf16x8 af1 = *(const bf16x8*)(xbf + ((r * 2 + ks) * 2 + 1) * 512 + lane * 8);
#pragma unroll
    for (int nt = 0; nt < 4; ++nt) {
      float f[8];
#pragma unroll
      for (int e = 0; e < 8; ++e) f[e] = pw[(g * 8 + e) * 64 + nt * 16 + col];
      uint4 uv;
      uv.x = packbf2(f[0], f[1]);
      uv.y = packbf2(f[2], f[3]);
      uv.z = packbf2(f[4], f[5]);
      uv.w = packbf2(f[6], f[7]);
      bf16x8 bfr = __builtin_bit_cast(bf16x8, uv);
      acc[0][nt] = __builtin_amdgcn_mfma_f32_16x16x32_bf16(af0, bfr, acc[0][nt], 0, 0, 0);
      acc[1][nt] = __builtin_amdgcn_mfma_f32_16x16x32_bf16(af1, bfr, acc[1][nt], 0, 0, 0);
    }
  };

  auto epilogue = [&](int rr, int buf) {
    // C/D layout (HW-verified m89/m91): col = lane&15, row = (lane>>4)*4 + reg.
    ushort* ep = (ushort*)&ldsW[buf][w][0];  // own panel, reads already done
#pragma unroll
    for (int mt = 0; mt < 2; ++mt)
#pragma unroll
      for (int nt = 0; nt < 4; ++nt)
#pragma unroll
        for (int reg = 0; reg < 4; ++reg)
          ep[(mt * 16 + g * 4 + reg) * 64 + nt * 16 + col] = (ushort)f2bf(acc[mt][nt][reg]);
    ushort* pp = priors + ((size_t)(k * NR + rblk * 8 + rr)) * 2048;
#pragma unroll
    for (int i = 0; i < 4; ++i) {
      uint4 v = *(const uint4*)(ep + lane * 8 + i * 512);
      *(uint4*)(pp + lane * 8 + i * 512) = v;
    }
  };

  stage(0, 0, 0);
  __syncthreads();
  for (int ti = 0; ti < 8; ++ti) {
#pragma unroll
    for (int mt = 0; mt < 2; ++mt)
#pragma unroll
      for (int nt = 0; nt < 4; ++nt) acc[mt][nt] = f32x4{0.f, 0.f, 0.f, 0.f};
    stage(ti, 1, 1);          // prefetch this r's second K-step
    compute(ti, 0, 0);
    __syncthreads();          // drains buf1 staging (own-wave vmcnt)
    if (ti < 7) stage(ti + 1, 0, 0);  // prefetch next r's first K-step
    compute(ti, 1, 1);
    epilogue(ti, 1);
    __syncthreads();
  }
}

// Routing pass (unchanged). Block per kb (k = kb>>5, b = kb&31).
// priors layout [k][r][b][o]. Lane: g = lane/8, sl = lane%8.
// PASS==1: phase A computes o0 = squash(mean_r p) in-block (priors read #1);
//          phase B: l = a_r = p.o0, stores a_r, writes o1 (priors read #2, L3-hot).
// PASS==2: l = a_r + p.o1; writes final output.
template <int PASS>
__global__ __launch_bounds__(256) void routing(const __hip_bfloat16* __restrict__ priors,
                                               float* __restrict__ Abuf,
                                               const float* __restrict__ o_prev,
                                               float* __restrict__ o_out) {
  __shared__ float o_lds[64];
  __shared__ float red_num[4][8][8];
  __shared__ float red_den[4];
  const int kb = blockIdx.x;
  const int k = kb >> 5, b = kb & 31;
  const int tid = threadIdx.x, w = tid >> 6, lane = tid & 63;
  const int g = lane >> 3, sl = lane & 7;
  const int rsub = w * 8 + g;
  const __hip_bfloat16* pbase = priors + (size_t)k * NR * NB * NO + (size_t)b * NO;
  float* ab = Abuf + (size_t)kb * NR;

  if (PASS == 1) {
    float sum[8];
#pragma unroll
    for (int j = 0; j < 8; ++j) sum[j] = 0.f;
    for (int it = 0; it < NR / 32; ++it) {
      const int r = it * 32 + rsub;
      uint4 pv = *(const uint4*)(pbase + (size_t)r * (NB * NO) + sl * 8);
      sum[0] += __builtin_bit_cast(float, pv.x << 16);
      sum[1] += __builtin_bit_cast(float, pv.x & 0xffff0000u);
      sum[2] += __builtin_bit_cast(float, pv.y << 16);
      sum[3] += __builtin_bit_cast(float, pv.y & 0xffff0000u);
      sum[4] += __builtin_bit_cast(float, pv.z << 16);
      sum[5] += __builtin_bit_cast(float, pv.z & 0xffff0000u);
      sum[6] += __builtin_bit_cast(float, pv.w << 16);
      sum[7] += __builtin_bit_cast(float, pv.w & 0xffff0000u);
    }
#pragma unroll
    for (int m = 8; m < 64; m <<= 1)
#pragma unroll
      for (int j = 0; j < 8; ++j) sum[j] += __shfl_xor(sum[j], m, 64);
    if (lane < 8) {
#pragma unroll
      for (int j = 0; j < 8; ++j) red_num[w][lane][j] = sum[j];
    }
    __syncthreads();
    if (tid < 64) {
      const int s_ = tid >> 3, j_ = tid & 7;
      float sv = (red_num[0][s_][j_] + red_num[1][s_][j_] +
                  red_num[2][s_][j_] + red_num[3][s_][j_]) * (1.f / (float)NR);
      float sq = sv * sv;
#pragma unroll
      for (int m = 1; m < 64; m <<= 1) sq += __shfl_xor(sq, m, 64);
      o_lds[tid] = (sq / (1.f + sq)) * rsqrtf(sq) * sv;  // squash
    }
    __syncthreads();
  } else {
    if (tid < 64) o_lds[tid] = o_prev[kb * 64 + tid];
    __syncthreads();
  }

  float os[8];
#pragma unroll
  for (int j = 0; j < 8; ++j) os[j] = o_lds[sl * 8 + j];

  float num[8];
#pragma unroll
  for (int j = 0; j < 8; ++j) num[j] = 0.f;
  float den = 0.f;

  for (int it = 0; it < NR / 32; ++it) {
    const int r = it * 32 + rsub;
    uint4 pv = *(const uint4*)(pbase + (size_t)r * (NB * NO) + sl * 8);
    float f[8];
    f[0] = __builtin_bit_cast(float, pv.x << 16);
    f[1] = __builtin_bit_cast(float, pv.x & 0xffff0000u);
    f[2] = __builtin_bit_cast(float, pv.y << 16);
    f[3] = __builtin_bit_cast(float, pv.y & 0xffff0000u);
    f[4] = __builtin_bit_cast(float, pv.z << 16);
    f[5] = __builtin_bit_cast(float, pv.z & 0xffff0000u);
    f[6] = __builtin_bit_cast(float, pv.w << 16);
    f[7] = __builtin_bit_cast(float, pv.w & 0xffff0000u);

    float d = 0.f;
#pragma unroll
    for (int j = 0; j < 8; ++j) d = fmaf(f[j], os[j], d);
#pragma unroll
    for (int m = 1; m < 8; m <<= 1) d += __shfl_xor(d, m, 64);

    float lg;
    if (PASS == 1) {
      lg = d;
      if (sl == 0) ab[r] = d;
    } else {
      lg = d + ab[r];
    }
    float e = __expf(lg);  // |lg| << 1, no max-subtraction needed
    den += e;
#pragma unroll
    for (int j = 0; j < 8; ++j) num[j] = fmaf(e, f[j], num[j]);
  }

#pragma unroll
  for (int m = 8; m < 64; m <<= 1) {
    den += __shfl_xor(den, m, 64);
#pragma unroll
    for (int j = 0; j < 8; ++j) num[j] += __shfl_xor(num[j], m, 64);
  }
  if (lane < 8) {
#pragma unroll
    for (int j = 0; j < 8; ++j) red_num[w][lane][j] = num[j];
    if (lane == 0) red_den[w] = den;
  }
  __syncthreads();

  if (tid < 64) {
    const int s_ = tid >> 3, j_ = tid & 7;
    float nm = red_num[0][s_][j_] + red_num[1][s_][j_] + red_num[2][s_][j_] + red_num[3][s_][j_];
    float dn = red_den[0] + red_den[1] + red_den[2] + red_den[3];
    float sv = nm / dn;
    float sq = sv * sv;
#pragma unroll
    for (int m = 1; m < 64; m <<= 1) sq += __shfl_xor(sq, m, 64);
    float ov = (sq / (1.f + sq)) * rsqrtf(sq) * sv;
    o_out[kb * 64 + tid] = ov;
  }
}

extern "C" void kernel_launch(void* const* d_in, const int* in_sizes, int n_in,
                              void* d_out, int out_size, void* d_ws, size_t ws_size,
                              hipStream_t stream) {
  const float* x = (const float*)d_in[0];          // [B][R][CIN]
  const float* W = (const float*)d_in[1];          // [K][R][CIN][COUT]
  float* out = (float*)d_out;                      // [K][B][COUT]
  char* ws = (char*)d_ws;

  size_t off = 0;
  ushort* xbf = (ushort*)(ws + off);               off += (size_t)NR * 2048 * 2;           // 8 MB
  ushort* priors = (ushort*)(ws + off);            off += (size_t)NK * NR * NB * NO * 2;   // 128 MB
  float* o1 = (float*)(ws + off);                  off += (size_t)NK * NB * NO * 4;        // 128 KB
  float* Abuf = (float*)(ws + off);                off += (size_t)NK * NB * NR * 4;        // 4 MB

  make_xbf<<<NR, 256, 0, stream>>>(x, xbf);
  priors_gemm<<<(NR / 8) * (NK / 4), 256, 0, stream>>>(xbf, W, priors);
  routing<1><<<NK * NB, 256, 0, stream>>>((const __hip_bfloat16*)priors, Abuf, nullptr, o1);
  routing<2><<<NK * NB, 256, 0, stream>>>((const __hip_bfloat16*)priors, Abuf, o1, out);
}